// Round 8
// baseline (172.288 us; speedup 1.0000x reference)
//
#include <hip/hip_runtime.h>
#include <hip/hip_fp16.h>

// WHTConv2D fused single-kernel: out = Rw(Rh(g(Rh(Rw(x))))) + x
//   Rw/Rh = normalized FWHT-256 along w/h (separable; order swapped vs ref, exact)
//   g(f)[h,w] = sum_p tanh(f*v_p) * relu(|f*v_p| - |T_p|)
// x: (8,64,256,256) f32 -> 512 planes of 256x256. One block per plane, whole
// plane staged in LDS as fp16 (128 KB static). v,T: (4,256,256) f32.
//
// Round-8 change (pass B was latency-bound: 128 scalar dword loads/thread of
// L2-resident v,T at 4 waves/SIMD, unroll-2 lookahead):
//  1. k_prep packs (v, |T|) into ONE half2 word in d_ws -> 64 u32 loads/thread,
//     L2 traffic 1 GB -> 512 MB, fabs folded at prep.
//  2. a-loop unroll 2 -> 4 (16 packed u32 in flight = same regs as before).
//  3. signed tanh identity drops fabsf/copysign from g_term.

#define NPX 65536   // pixels per plane
#define SC  0.0625f // 1/sqrt(256)

__device__ __forceinline__ unsigned int h2u(__half2 h) {
  union { __half2 h; unsigned int u; } c; c.h = h; return c.u;
}
__device__ __forceinline__ __half2 u2h(unsigned int u) {
  union { __half2 h; unsigned int u; } c; c.u = u; return c.h;
}

// 16-point unnormalized FWHT fully in registers.
__device__ __forceinline__ void fwht16(float f[16]) {
  #pragma unroll
  for (int d = 1; d < 16; d <<= 1) {
    #pragma unroll
    for (int i = 0; i < 16; ++i) {
      if (!(i & d)) {
        float a = f[i], b = f[i | d];
        f[i]     = a + b;
        f[i | d] = a - b;
      }
    }
  }
}

// 256-point unnormalized FWHT across one wave; lane holds elems i = 4*lane + j.
__device__ __forceinline__ void fwht256_wave(float r[4], int lane) {
  float a0 = r[0] + r[1], b0 = r[0] - r[1];
  float a1 = r[2] + r[3], b1 = r[2] - r[3];
  r[0] = a0 + a1; r[1] = b0 + b1; r[2] = a0 - a1; r[3] = b0 - b1;
  #pragma unroll
  for (int m = 1; m <= 32; m <<= 1) {
    const float s = (lane & m) ? -1.0f : 1.0f;
    #pragma unroll
    for (int j = 0; j < 4; ++j) {
      float t = __shfl_xor(r[j], m);
      r[j] = fmaf(r[j], s, t);   // low lane: r+t ; high lane: t-r
    }
  }
}

// g term with signed tanh: tanh(a)*relu(|a|-absT)
__device__ __forceinline__ float g_term(float a, float absT) {
  float e  = __builtin_amdgcn_exp2f(a * 2.8853900817779268f);  // exp(2a)
  float th = 1.0f - 2.0f * __builtin_amdgcn_rcpf(e + 1.0f);    // tanh(a), sign-correct
  float rl = fmaxf(fabsf(a) - absT, 0.0f);                     // fabs = free src modifier
  return th * rl;
}

// ---- prep: W[p][pix] = half2(v, |T|) packed in one u32 ----
__global__ __launch_bounds__(256) void k_prep(const float* __restrict__ v,
                                              const float* __restrict__ T,
                                              unsigned int* __restrict__ W) {
  const int i = 4 * (blockIdx.x * 256 + threadIdx.x);   // 4*65536 total / 4 per thread
  const float4 v4 = *reinterpret_cast<const float4*>(v + i);
  const float4 t4 = *reinterpret_cast<const float4*>(T + i);
  uint4 w;
  w.x = h2u(__floats2half2_rn(v4.x, fabsf(t4.x)));
  w.y = h2u(__floats2half2_rn(v4.y, fabsf(t4.y)));
  w.z = h2u(__floats2half2_rn(v4.z, fabsf(t4.z)));
  w.w = h2u(__floats2half2_rn(v4.w, fabsf(t4.w)));
  *reinterpret_cast<uint4*>(W + i) = w;
}

__global__ __launch_bounds__(1024) void k_fused(const float* __restrict__ x,
                                                const unsigned int* __restrict__ W,
                                                float* __restrict__ out) {
  __shared__ __half S[256 * 256];          // 128 KiB static, pitch 256
  const int tid  = threadIdx.x;
  const int lane = tid & 63;
  const int wv   = tid >> 6;               // wave id 0..15
  const size_t pbase = (size_t)blockIdx.x * NPX;

  // ---- phase 1: row FWHT of x -> LDS (fp16, x SC) ----
  #pragma unroll 2
  for (int rr = 0; rr < 16; ++rr) {
    const int row = wv * 16 + rr;
    const float4 xv = *reinterpret_cast<const float4*>(x + pbase + (size_t)row * 256 + 4 * lane);
    float r[4] = {xv.x, xv.y, xv.z, xv.w};
    fwht256_wave(r, lane);
    uint2 pk;
    pk.x = h2u(__floats2half2_rn(r[0] * SC, r[1] * SC));
    pk.y = h2u(__floats2half2_rn(r[2] * SC, r[3] * SC));
    *reinterpret_cast<uint2*>(&S[row * 256 + 4 * lane]) = pk;
  }
  __syncthreads();

  // ---- phase 2: column Rh o g o Rh, radix-16 (h = 16a + k) ----
  const int q = tid & 63;                  // for passes A/C (column pairs)
  const int g = tid >> 6;                  // wave-uniform row group, passes A/C
  const int c   = tid & 255;               // for pass B (single column)
  const int grp = tid >> 8;                // 0..3, pass B g-subset
  float fp[2][16];

  // pass A: FWHT16 over k (contiguous rows 16g+k); two half-sweeps, b32 LDS
  #pragma unroll 1
  for (int hs = 0; hs < 2; ++hs) {
    const int cb = 2 * q + 128 * hs;
    #pragma unroll
    for (int k = 0; k < 16; ++k) {
      unsigned int d = *reinterpret_cast<unsigned int*>(&S[(16 * g + k) * 256 + cb]);
      float2 e = __half22float2(u2h(d));
      fp[0][k] = e.x; fp[1][k] = e.y;
    }
    fwht16(fp[0]); fwht16(fp[1]);
    #pragma unroll
    for (int k = 0; k < 16; ++k) {
      *reinterpret_cast<unsigned int*>(&S[(16 * g + k) * 256 + cb]) =
          h2u(__floats2half2_rn(fp[0][k], fp[1][k]));
    }
  }
  __syncthreads();

  // pass B: rows gg+16a: FWHT16 over a (completes Rh1) -> xSC -> g -> FWHT16
  // over a (first half of Rh2) -> xSC -> back to LDS.
  // Four quarter-sweeps of ONE column: f[16] live, packed (v,|T|) u32 loads.
  {
    float f[16];
    #pragma unroll 1
    for (int gg = grp; gg < 16; gg += 4) {
      #pragma unroll
      for (int a = 0; a < 16; ++a)
        f[a] = __half2float(S[(gg + 16 * a) * 256 + c]);
      fwht16(f);
      #pragma unroll
      for (int a = 0; a < 16; ++a) f[a] *= SC;

      #pragma unroll 4
      for (int a = 0; a < 16; ++a) {
        const int off = (gg + 16 * a) * 256 + c;
        float acc = 0.f;
        #pragma unroll
        for (int p = 0; p < 4; ++p) {
          const float2 w = __half22float2(u2h(W[p * NPX + off]));  // (v, |T|)
          acc += g_term(f[a] * w.x, w.y);
        }
        f[a] = acc;
      }

      fwht16(f);
      #pragma unroll
      for (int a = 0; a < 16; ++a)
        S[(gg + 16 * a) * 256 + c] = __float2half_rn(f[a] * SC);
    }
  }
  __syncthreads();

  // pass C: FWHT16 over k (second half of Rh2; scale already applied)
  #pragma unroll 1
  for (int hs = 0; hs < 2; ++hs) {
    const int cb = 2 * q + 128 * hs;
    #pragma unroll
    for (int k = 0; k < 16; ++k) {
      unsigned int d = *reinterpret_cast<unsigned int*>(&S[(16 * g + k) * 256 + cb]);
      float2 e = __half22float2(u2h(d));
      fp[0][k] = e.x; fp[1][k] = e.y;
    }
    fwht16(fp[0]); fwht16(fp[1]);
    #pragma unroll
    for (int k = 0; k < 16; ++k) {
      *reinterpret_cast<unsigned int*>(&S[(16 * g + k) * 256 + cb]) =
          h2u(__floats2half2_rn(fp[0][k], fp[1][k]));
    }
  }
  __syncthreads();

  // ---- phase 3: row FWHT (x SC) + x residual -> out ----
  #pragma unroll 2
  for (int rr = 0; rr < 16; ++rr) {
    const int row = wv * 16 + rr;
    uint2 pk = *reinterpret_cast<uint2*>(&S[row * 256 + 4 * lane]);
    float2 lo = __half22float2(u2h(pk.x));
    float2 hi = __half22float2(u2h(pk.y));
    float r[4] = {lo.x, lo.y, hi.x, hi.y};
    fwht256_wave(r, lane);
    const float4 xv = *reinterpret_cast<const float4*>(x + pbase + (size_t)row * 256 + 4 * lane);
    float4 o;
    o.x = fmaf(r[0], SC, xv.x);
    o.y = fmaf(r[1], SC, xv.y);
    o.z = fmaf(r[2], SC, xv.z);
    o.w = fmaf(r[3], SC, xv.w);
    *reinterpret_cast<float4*>(out + pbase + (size_t)row * 256 + 4 * lane) = o;
  }
}

extern "C" void kernel_launch(void* const* d_in, const int* in_sizes, int n_in,
                              void* d_out, int out_size, void* d_ws, size_t ws_size,
                              hipStream_t stream) {
  const float* x = (const float*)d_in[0];
  const float* v = (const float*)d_in[1];
  const float* T = (const float*)d_in[2];
  float* out = (float*)d_out;
  unsigned int* W = (unsigned int*)d_ws;   // 1 MB packed (v,|T|) fp16

  k_prep<<<256, 256, 0, stream>>>(v, T, W);
  k_fused<<<512, 1024, 0, stream>>>(x, W, out);
}